// Round 1
// baseline (222.261 us; speedup 1.0000x reference)
//
#include <hip/hip_runtime.h>

#define NVOC 65
#define NE   32
#define HD   16
#define NB   65536
#define NROWS (NB * 8)                   // 524288
#define NLOG  (NROWS * NVOC)             // 34078720

// LDS layout (floats), single fused kernel:
//  final tables (unchanged offsets vs previous ws layout):
//    G1@0(4225) TVL@4225(4225) G2@8450(520) G3@8970(520) G4@9490(64) PVL@9554(520)
//  scratch (alive only until tables built):
//    TQ@10076(1040) TK@11116(1040) TV@12156(1040) WLM@13196(1040)
//    PQ@14236(128) PK@14364(128) PV@14492(128)   -> S[14620], 58.5 KB
//  phase-1 staging (dies before table sweep overwrites it): tok@0(2080) pos@2080(256)
//    Wq@2336(512) Wk@2848(512) Wv@3360(512)
#define TQ_  10076
#define TK_  11116
#define TV_  12156
#define WLM_ 13196
#define PQ_  14236
#define PK_  14364
#define PV_  14492
#define SEND 14620

static __device__ __forceinline__ float readlane_f(float v, int l) {
  return __uint_as_float(__builtin_amdgcn_readlane(__float_as_uint(v), l));
}

// ---- fused kernel: 1024 blocks x 512 threads; each block builds its own tables
//      (~0.5 us redundant compute) then runs the main loop. 58.5 KB LDS -> 2 blocks/CU.
__global__ __launch_bounds__(512, 4) void bigram_all(
    const int* __restrict__ idx, const int* __restrict__ tgt,
    const float* __restrict__ tok, const float* __restrict__ pos,
    const float* __restrict__ Wk, const float* __restrict__ bk,
    const float* __restrict__ Wq, const float* __restrict__ bq,
    const float* __restrict__ Wv, const float* __restrict__ bv,
    const float* __restrict__ Wlm, const float* __restrict__ blm,
    float* __restrict__ ws, float* __restrict__ out)
{
  __shared__ __align__(16) float S[SEND];
  __shared__ float red[8];
  const int tid  = threadIdx.x;
  const int lane = tid & 63;
  const int w    = tid >> 6;                 // 0..7
  const int t    = lane >> 3;
  const int s    = lane & 7;
  const int gw   = blockIdx.x * 8 + w;       // 8192 waves total
  // issue data-loads early; they only depend on globals
  const int iv = idx[gw*64 + lane];
  const int tv = tgt[gw*64 + lane];
  const float blmj  = blm[lane];
  const float blm64 = blm[64];

  // ---- phase 1: stage weights (19.6 KB, L2/L3-resident) ----
  {
    float4* s4 = (float4*)S;
    const float4* t4;
    t4 = (const float4*)tok; for (int o = tid; o < 520; o += 512) s4[o] = t4[o];
    t4 = (const float4*)pos; if (tid < 64)  s4[520 + tid] = t4[tid];
    t4 = (const float4*)Wq;  if (tid < 128) s4[584 + tid] = t4[tid];
    t4 = (const float4*)Wk;  if (tid < 128) s4[712 + tid] = t4[tid];
    t4 = (const float4*)Wv;  if (tid < 128) s4[840 + tid] = t4[tid];
    t4 = (const float4*)Wlm; for (int o = tid; o < 260; o += 512) s4[3299 + o] = t4[o];
  }
  __syncthreads();

  // ---- phase 2: token/position Q,K,V projections into scratch ----
  for (int o = tid; o < 1168; o += 512) {
    if (o < 1040) {
      const int a = o >> 4, h = o & 15;
      float sq = 0.f, sk = 0.f, sv = 0.f;
      #pragma unroll
      for (int c = 0; c < NE; ++c) {
        const float e = S[a*32 + c];
        sq = fmaf(e, S[2336 + c*16 + h], sq);
        sk = fmaf(e, S[2848 + c*16 + h], sk);
        sv = fmaf(e, S[3360 + c*16 + h], sv);
      }
      S[TQ_ + o] = sq; S[TK_ + o] = sk; S[TV_ + o] = sv;
    } else {
      const int o2 = o - 1040, tp = o2 >> 4, h = o2 & 15;
      float sq = bq[h], sk = bk[h], sv = bv[h];
      #pragma unroll
      for (int c = 0; c < NE; ++c) {
        const float e = S[2080 + tp*32 + c];
        sq = fmaf(e, S[2336 + c*16 + h], sq);
        sk = fmaf(e, S[2848 + c*16 + h], sk);
        sv = fmaf(e, S[3360 + c*16 + h], sv);
      }
      S[PQ_ + o2] = sq; S[PK_ + o2] = sk; S[PV_ + o2] = sv;
    }
  }
  __syncthreads();

  // ---- phase 3: all lookup tables. Reads only scratch [10076..), writes [0..10074)
  //      (overwrites dead staging) -> no intra-sweep hazard. Same expression
  //      order as the old tables kernel => bitwise-identical results.
  for (int o = tid; o < 10074; o += 512) {
    float r = 0.f;
    if (o < 4225) {                       // G1[a][b] = 0.25 * TQ[a].TK[b]
      const int a = o / 65, b = o % 65;
      #pragma unroll
      for (int h = 0; h < HD; ++h) r = fmaf(S[TQ_ + a*16 + h], S[TK_ + b*16 + h], r);
      r *= 0.25f;
    } else if (o < 8450) {                // TVL[a][j] = TV[a].Wlm[:,j]
      const int o2 = o - 4225, a = o2 / 65, j = o2 % 65;
      #pragma unroll
      for (int h = 0; h < HD; ++h) r = fmaf(S[TV_ + a*16 + h], S[WLM_ + h*65 + j], r);
    } else if (o < 8970) {                // G2[a][s]
      const int o2 = o - 8450, a = o2 >> 3, s2 = o2 & 7;
      #pragma unroll
      for (int h = 0; h < HD; ++h) r = fmaf(S[TQ_ + a*16 + h], S[PK_ + s2*16 + h], r);
      r *= 0.25f;
    } else if (o < 9490) {                // G3[t][b]
      const int o2 = o - 8970, t2 = o2 / 65, b = o2 % 65;
      #pragma unroll
      for (int h = 0; h < HD; ++h) r = fmaf(S[PQ_ + t2*16 + h], S[TK_ + b*16 + h], r);
      r *= 0.25f;
    } else if (o < 9554) {                // G4[t][s]
      const int o2 = o - 9490, t2 = o2 >> 3, s2 = o2 & 7;
      #pragma unroll
      for (int h = 0; h < HD; ++h) r = fmaf(S[PQ_ + t2*16 + h], S[PK_ + s2*16 + h], r);
      r *= 0.25f;
    } else {                              // PVL[s][j]
      const int o2 = o - 9554, s2 = o2 / 65, j = o2 % 65;
      #pragma unroll
      for (int h = 0; h < HD; ++h) r = fmaf(S[PV_ + s2*16 + h], S[WLM_ + h*65 + j], r);
    }
    S[o] = r;
  }
  __syncthreads();

  // ---- main loop (unchanged) ----
  const float g4 = S[9490 + lane];           // G4[t][s], lane == t*8+s
  float pvl[8], pvl64[8];
  #pragma unroll
  for (int k = 0; k < 8; ++k) {
    pvl[k]   = S[9554 + k*65 + lane];        // PVL[s=k][j=lane]
    pvl64[k] = S[9554 + k*65 + 64];
  }

  float acc_lsm = 0.f, acc_tl = 0.f;
  for (int itb = 0; itb < 8; ++itb) {
    const int base = itb * 8;
    const int av  = __shfl(iv, base + s);    // token at key position s
    const int a_t = __shfl(iv, base + t);    // token at query position t
    // scaled causal score, lane = (t,s)
    float wr = S[a_t*65 + av] + S[8450 + a_t*8 + s] + S[8970 + t*65 + av] + g4;
    float e = (t >= s) ? __expf(wr) : 0.f;   // softmax over t (per column s)
    float sm = e;
    sm += __shfl_xor(sm, 8); sm += __shfl_xor(sm, 16); sm += __shfl_xor(sm, 32);
    const float wsm = __fdividef(e, sm);     // wei[t][s] at lane t*8+s
    // M[k][j=lane] = TVL[a_k][j] + PVL[k][j]; col 64 uniform across lanes
    float Ms[8], Ms64[8];
    #pragma unroll
    for (int k = 0; k < 8; ++k) {
      const int ak = __builtin_amdgcn_readlane(iv, base + k);
      Ms[k]   = S[4225 + ak*65 + lane] + pvl[k];
      Ms64[k] = S[4225 + ak*65 + 64]  + pvl64[k];
    }
    const int rowbase = (gw*8 + itb) * 520;
    float ee[8];
    #pragma unroll
    for (int tt = 0; tt < 8; ++tt) {
      float lg = blmj, lg64 = blm64;
      #pragma unroll
      for (int k = 0; k < 8; ++k) {
        const float wk = readlane_f(wsm, tt*8 + k);   // wei[tt][k]
        lg   = fmaf(wk, Ms[k],   lg);
        lg64 = fmaf(wk, Ms64[k], lg64);
      }
      out[rowbase + tt*65 + lane] = lg;
      if (lane == 63) out[rowbase + tt*65 + 64] = lg64;
      float x = __expf(lg);
      if (lane == 63) x += __expf(lg64);     // fold col 64 into lane 63
      ee[tt] = x;
      const int tg  = __builtin_amdgcn_readlane(tv, base + tt);
      const int tgc = tg < 64 ? tg : 0;
      const float l_at_tg = readlane_f(lg, tgc);
      acc_tl += (tg < 64) ? l_at_tg : lg64;  // uniform across lanes
    }
    // row sums: reduce each ee[tt] within the 8-lane octet (xor 1,2,4),
    // select r = ee[u] (u = lane&7), then reduce across octets (xor 8,16,32).
    #pragma unroll
    for (int tt = 0; tt < 8; ++tt) {
      ee[tt] += __shfl_xor(ee[tt], 1);
      ee[tt] += __shfl_xor(ee[tt], 2);
      ee[tt] += __shfl_xor(ee[tt], 4);
    }
    const int u = lane & 7;
    float r01 = (u & 1) ? ee[1] : ee[0];
    float r23 = (u & 1) ? ee[3] : ee[2];
    float r45 = (u & 1) ? ee[5] : ee[4];
    float r67 = (u & 1) ? ee[7] : ee[6];
    float r03 = (u & 2) ? r23 : r01;
    float r47 = (u & 2) ? r67 : r45;
    float r   = (u & 4) ? r47 : r03;
    r += __shfl_xor(r, 8); r += __shfl_xor(r, 16); r += __shfl_xor(r, 32);
    acc_lsm += __logf(r);                    // row u, 8 lane-copies per row
  }
  float v = acc_lsm * 0.125f - acc_tl * 0.015625f;
  v += __shfl_xor(v, 1); v += __shfl_xor(v, 2);  v += __shfl_xor(v, 4);
  v += __shfl_xor(v, 8); v += __shfl_xor(v, 16); v += __shfl_xor(v, 32);
  if (lane == 0) red[w] = v;
  __syncthreads();
  if (tid == 0) {
    // poison-safe: plain store of this block's partial (no atomics, no init needed)
    ws[blockIdx.x] = red[0] + red[1] + red[2] + red[3]
                   + red[4] + red[5] + red[6] + red[7];
  }
}

// ---- final reduction: sum 1024 block partials -> loss ----
__global__ __launch_bounds__(1024) void bigram_fin2(
    const float* __restrict__ ws, float* __restrict__ out)
{
  __shared__ float r[16];
  const int tid = threadIdx.x;
  float v = ws[tid];
  v += __shfl_xor(v, 1); v += __shfl_xor(v, 2);  v += __shfl_xor(v, 4);
  v += __shfl_xor(v, 8); v += __shfl_xor(v, 16); v += __shfl_xor(v, 32);
  if ((tid & 63) == 0) r[tid >> 6] = v;
  __syncthreads();
  if (tid == 0) {
    float a = 0.f;
    #pragma unroll
    for (int i = 0; i < 16; ++i) a += r[i];
    out[NLOG] = a * (1.0f / (float)NROWS);
  }
}

extern "C" void kernel_launch(void* const* d_in, const int* in_sizes, int n_in,
                              void* d_out, int out_size, void* d_ws, size_t ws_size,
                              hipStream_t stream) {
  bigram_all<<<1024, 512, 0, stream>>>(
      (const int*)d_in[0], (const int*)d_in[1],
      (const float*)d_in[2], (const float*)d_in[3],
      (const float*)d_in[4], (const float*)d_in[5],
      (const float*)d_in[6], (const float*)d_in[7],
      (const float*)d_in[8], (const float*)d_in[9],
      (const float*)d_in[10], (const float*)d_in[11],
      (float*)d_ws, (float*)d_out);
  bigram_fin2<<<1, 1024, 0, stream>>>((const float*)d_ws, (float*)d_out);
}

// Round 2
// 200.701 us; speedup vs baseline: 1.1074x; 1.1074x over previous
//
#include <hip/hip_runtime.h>

#define NVOC 65
#define NE   32
#define HD   16
#define NB   65536
#define NROWS (NB * 8)                   // 524288
#define NLOG  (NROWS * NVOC)             // 34078720

// ws layout (floats): wsTab = ws+16 (64B aligned), 10074 floats:
//   G1@0(4225) TVL@4225(4225) G2@8450(520) G3@8970(520) G4@9490(64) PVL@9554(520)
// block partials: ws[10112 .. 10112+1024)

static __device__ __forceinline__ float readlane_f(float v, int l) {
  return __uint_as_float(__builtin_amdgcn_readlane(__float_as_uint(v), l));
}

// ---- tables kernel: ONE block of 1024 threads; builds all lookup tables into ws ----
__global__ __launch_bounds__(1024) void bigram_tables(
    const float* __restrict__ tok, const float* __restrict__ pos,
    const float* __restrict__ Wk, const float* __restrict__ bk,
    const float* __restrict__ Wq, const float* __restrict__ bq,
    const float* __restrict__ Wv, const float* __restrict__ bv,
    const float* __restrict__ Wlm, float* __restrict__ ws)
{
  // LDS: tok@0(2080) pos@2080(256) Wq@2336(512) Wk@2848(512) Wv@3360(512)
  //      Wlm@3872(1040) TQ@4912(1040) TK@5952(1040) TV@6992(1040)
  //      PQ@8032(128) PK@8160(128) PV@8288(128)  -> 8416 floats
  __shared__ float S[8416];
  const int tid = threadIdx.x;
  for (int o = tid; o < 2080; o += 1024) S[o] = tok[o];
  for (int o = tid; o < 256;  o += 1024) S[2080 + o] = pos[o];
  for (int o = tid; o < 512;  o += 1024) {
    S[2336 + o] = Wq[o]; S[2848 + o] = Wk[o]; S[3360 + o] = Wv[o];
  }
  for (int o = tid; o < 1040; o += 1024) S[3872 + o] = Wlm[o];
  __syncthreads();

  for (int o = tid; o < 1168; o += 1024) {
    if (o < 1040) {
      const int a = o >> 4, h = o & 15;
      float sq = 0.f, sk = 0.f, sv = 0.f;
      #pragma unroll
      for (int c = 0; c < NE; ++c) {
        const float e = S[a*32 + c];
        sq = fmaf(e, S[2336 + c*16 + h], sq);
        sk = fmaf(e, S[2848 + c*16 + h], sk);
        sv = fmaf(e, S[3360 + c*16 + h], sv);
      }
      S[4912 + o] = sq; S[5952 + o] = sk; S[6992 + o] = sv;
    } else {
      const int o2 = o - 1040, t = o2 >> 4, h = o2 & 15;
      float sq = bq[h], sk = bk[h], sv = bv[h];
      #pragma unroll
      for (int c = 0; c < NE; ++c) {
        const float e = S[2080 + t*32 + c];
        sq = fmaf(e, S[2336 + c*16 + h], sq);
        sk = fmaf(e, S[2848 + c*16 + h], sk);
        sv = fmaf(e, S[3360 + c*16 + h], sv);
      }
      S[8032 + o2] = sq; S[8160 + o2] = sk; S[8288 + o2] = sv;
    }
  }
  __syncthreads();

  float* wsTab = ws + 16;
  for (int o = tid; o < 10074; o += 1024) {
    float r = 0.f; int dst;
    if (o < 4225) {                       // G1[a][b] = 0.25 * TQ[a].TK[b]
      const int a = o / 65, b = o % 65;
      #pragma unroll
      for (int h = 0; h < HD; ++h) r = fmaf(S[4912 + a*16 + h], S[5952 + b*16 + h], r);
      r *= 0.25f; dst = o;
    } else if (o < 4745) {                // G2[a][s]
      const int o2 = o - 4225, a = o2 >> 3, s2 = o2 & 7;
      #pragma unroll
      for (int h = 0; h < HD; ++h) r = fmaf(S[4912 + a*16 + h], S[8160 + s2*16 + h], r);
      r *= 0.25f; dst = 8450 + o2;
    } else if (o < 5265) {                // G3[t][b]
      const int o2 = o - 4745, t2 = o2 / 65, b = o2 % 65;
      #pragma unroll
      for (int h = 0; h < HD; ++h) r = fmaf(S[8032 + t2*16 + h], S[5952 + b*16 + h], r);
      r *= 0.25f; dst = 8970 + o2;
    } else if (o < 5329) {                // G4[t][s]
      const int o2 = o - 5265, t2 = o2 >> 3, s2 = o2 & 7;
      #pragma unroll
      for (int h = 0; h < HD; ++h) r = fmaf(S[8032 + t2*16 + h], S[8160 + s2*16 + h], r);
      r *= 0.25f; dst = 9490 + o2;
    } else if (o < 9554) {                // TVL[a][j]
      const int o2 = o - 5329, a = o2 / 65, j = o2 % 65;
      #pragma unroll
      for (int h = 0; h < HD; ++h) r = fmaf(S[6992 + a*16 + h], S[3872 + h*65 + j], r);
      dst = 4225 + o2;
    } else {                              // PVL[s][j]
      const int o2 = o - 9554, s2 = o2 / 65, j = o2 % 65;
      #pragma unroll
      for (int h = 0; h < HD; ++h) r = fmaf(S[8288 + s2*16 + h], S[3872 + h*65 + j], r);
      dst = o;
    }
    wsTab[dst] = r;
  }
}

// ---- main kernel: 1024 blocks x 512 threads; 1 wave handles 8 batches ----
// LDS = 10082 floats = 40.3 KB -> 4 blocks/CU (32 waves/CU, HW max occupancy).
__global__ __launch_bounds__(512, 8) void bigram_main(
    const int* __restrict__ idx, const int* __restrict__ tgt,
    const float* __restrict__ blm, const float* __restrict__ ws,
    float* __restrict__ wsout, float* __restrict__ out)
{
  __shared__ __align__(16) float S[10074];
  __shared__ float red[8];
  const int tid = threadIdx.x;
  const int lane = tid & 63;
  const int w    = tid >> 6;                 // 0..7
  const int t    = lane >> 3;
  const int s    = lane & 7;
  const int u    = lane & 7;
  const int gw = blockIdx.x * 8 + w;         // 8192 waves total
  const int iv = idx[gw*64 + lane];          // element (itb*8+p) lives at lane itb*8+p
  const int tv = tgt[gw*64 + lane];
  const float blmj  = blm[lane];
  const float blm64 = blm[64];
  const float* wsTab = ws + 16;
  {
    const float4* t4 = (const float4*)wsTab;
    float4* s4 = (float4*)S;
    for (int o = tid; o < 2518; o += 512) s4[o] = t4[o];   // 10072 floats
    if (tid < 2) S[10072 + tid] = wsTab[10072 + tid];
  }
  __syncthreads();

  const float g4 = S[9490 + lane];           // G4[t][s], lane == t*8+s
  float pvl[8], pvl64[8];
  #pragma unroll
  for (int k = 0; k < 8; ++k) {
    pvl[k]   = S[9554 + k*65 + lane];        // PVL[s=k][j=lane]
    pvl64[k] = S[9554 + k*65 + 64];
  }

  float acc_lsm = 0.f, acc_tl = 0.f;
  for (int itb = 0; itb < 8; ++itb) {
    const int base = itb * 8;
    const int av  = __shfl(iv, base + s);    // token at key position s
    const int a_t = __shfl(iv, base + t);    // token at query position t
    // scaled causal score, lane = (t,s)
    float wr = S[a_t*65 + av] + S[8450 + a_t*8 + s] + S[8970 + t*65 + av] + g4;
    float e = (t >= s) ? __expf(wr) : 0.f;   // softmax over t (per column s)
    float sm = e;
    sm += __shfl_xor(sm, 8); sm += __shfl_xor(sm, 16); sm += __shfl_xor(sm, 32);
    const float wsm = __fdividef(e, sm);     // wei[t][s] at lane t*8+s
    // M[k][j=lane] = TVL[a_k][j] + PVL[k][j]; col 64 uniform across lanes
    float Ms[8], Ms64[8];
    #pragma unroll
    for (int k = 0; k < 8; ++k) {
      const int ak = __builtin_amdgcn_readlane(iv, base + k);
      Ms[k]   = S[4225 + ak*65 + lane] + pvl[k];
      Ms64[k] = S[4225 + ak*65 + 64]  + pvl64[k];
    }
    // col-64 logit for row (lane&7), computed ONCE per itb (not 64 uniform FMAs):
    // lane l needs wei[l&7][k] = wsm @ lane ((l&7)*8 + k)  -> ds_bpermute
    float lg64v = blm64;
    #pragma unroll
    for (int k = 0; k < 8; ++k) {
      const float wk_row = __shfl(wsm, u*8 + k);
      lg64v = fmaf(wk_row, Ms64[k], lg64v);
    }
    const int rowbase = (gw*8 + itb) * 520;
    if (lane < 8) out[rowbase + lane*65 + 64] = lg64v;   // one masked store, 8 rows
    float ee[8];
    #pragma unroll
    for (int tt = 0; tt < 8; ++tt) {
      float lg = blmj;
      #pragma unroll
      for (int k = 0; k < 8; ++k) {
        const float wk = readlane_f(wsm, tt*8 + k);   // wei[tt][k]
        lg = fmaf(wk, Ms[k], lg);
      }
      out[rowbase + tt*65 + lane] = lg;
      ee[tt] = __expf(lg);
      const int tg  = __builtin_amdgcn_readlane(tv, base + tt);
      const int tgc = tg < 64 ? tg : 0;
      const float l_at_tg = readlane_f(lg, tgc);
      const float l64t    = readlane_f(lg64v, tt);    // lane tt holds row tt's col64
      acc_tl += (tg < 64) ? l_at_tg : l64t;           // uniform across lanes
    }
    // row sums: reduce each ee[tt] within the 8-lane octet (xor 1,2,4),
    // select r = ee[u] (u = lane&7), then reduce across octets (xor 8,16,32).
    #pragma unroll
    for (int tt = 0; tt < 8; ++tt) {
      ee[tt] += __shfl_xor(ee[tt], 1);
      ee[tt] += __shfl_xor(ee[tt], 2);
      ee[tt] += __shfl_xor(ee[tt], 4);
    }
    float r01 = (u & 1) ? ee[1] : ee[0];
    float r23 = (u & 1) ? ee[3] : ee[2];
    float r45 = (u & 1) ? ee[5] : ee[4];
    float r67 = (u & 1) ? ee[7] : ee[6];
    float r03 = (u & 2) ? r23 : r01;
    float r47 = (u & 2) ? r67 : r45;
    float r   = (u & 4) ? r47 : r03;
    // fold col-64 exp exactly once per row: octet 0's lane l is row l
    if (lane < 8) r += __expf(lg64v);
    r += __shfl_xor(r, 8); r += __shfl_xor(r, 16); r += __shfl_xor(r, 32);
    acc_lsm += __logf(r);                    // row u, 8 lane-copies per row
  }
  float v = acc_lsm * 0.125f - acc_tl * 0.015625f;
  v += __shfl_xor(v, 1); v += __shfl_xor(v, 2);  v += __shfl_xor(v, 4);
  v += __shfl_xor(v, 8); v += __shfl_xor(v, 16); v += __shfl_xor(v, 32);
  if (lane == 0) red[w] = v;
  __syncthreads();
  if (tid == 0) {
    // poison-safe: plain store of this block's partial (no atomics, no init needed)
    wsout[10112 + blockIdx.x] = red[0] + red[1] + red[2] + red[3]
                              + red[4] + red[5] + red[6] + red[7];
  }
}

// ---- final reduction: sum 1024 block partials -> loss ----
__global__ __launch_bounds__(1024) void bigram_fin2(
    const float* __restrict__ ws, float* __restrict__ out)
{
  __shared__ float r[16];
  const int tid = threadIdx.x;
  float v = ws[10112 + tid];
  v += __shfl_xor(v, 1); v += __shfl_xor(v, 2);  v += __shfl_xor(v, 4);
  v += __shfl_xor(v, 8); v += __shfl_xor(v, 16); v += __shfl_xor(v, 32);
  if ((tid & 63) == 0) r[tid >> 6] = v;
  __syncthreads();
  if (tid == 0) {
    float a = 0.f;
    #pragma unroll
    for (int i = 0; i < 16; ++i) a += r[i];
    out[NLOG] = a * (1.0f / (float)NROWS);
  }
}

extern "C" void kernel_launch(void* const* d_in, const int* in_sizes, int n_in,
                              void* d_out, int out_size, void* d_ws, size_t ws_size,
                              hipStream_t stream) {
  const int* idx = (const int*)d_in[0];
  const int* tgt = (const int*)d_in[1];
  float* ws = (float*)d_ws;
  float* out = (float*)d_out;

  bigram_tables<<<1, 1024, 0, stream>>>((const float*)d_in[2], (const float*)d_in[3],
                                        (const float*)d_in[4], (const float*)d_in[5],
                                        (const float*)d_in[6], (const float*)d_in[7],
                                        (const float*)d_in[8], (const float*)d_in[9],
                                        (const float*)d_in[10], ws);
  bigram_main<<<1024, 512, 0, stream>>>(idx, tgt, (const float*)d_in[11], ws, ws, out);
  bigram_fin2<<<1, 1024, 0, stream>>>(ws, out);
}